// Round 4
// baseline (1626.959 us; speedup 1.0000x reference)
//
#include <hip/hip_runtime.h>
#include <stdint.h>

#define LEAKY 0.1f
typedef unsigned short u16;
typedef unsigned int u32;

// ---------- bf16 helpers (storage = ushort) ----------
__device__ __forceinline__ float bflo(u32 u){ union{u32 i; float f;} c; c.i = u<<16; return c.f; }
__device__ __forceinline__ float bfhi(u32 u){ union{u32 i; float f;} c; c.i = u & 0xffff0000u; return c.f; }
__device__ __forceinline__ float bf2f(u16 v){ union{u32 i; float f;} c; c.i = ((u32)v)<<16; return c.f; }
__device__ __forceinline__ u16 f2bf(float f){
  union{float f; u32 i;} c; c.f = f;
  u32 r = (c.i + 0x7fffu + ((c.i>>16)&1u)) >> 16;
  return (u16)r;
}
__device__ __forceinline__ u32 pack2(float a, float b){ return (u32)f2bf(a) | ((u32)f2bf(b)<<16); }

__device__ __forceinline__ void load8f(const float* p, float* v){
  const float4* q = (const float4*)p; float4 a = q[0], b = q[1];
  v[0]=a.x;v[1]=a.y;v[2]=a.z;v[3]=a.w;v[4]=b.x;v[5]=b.y;v[6]=b.z;v[7]=b.w;
}
__device__ __forceinline__ void load8h(const u16* p, float* v){
  uint4 u = *(const uint4*)p;
  v[0]=bflo(u.x);v[1]=bfhi(u.x);v[2]=bflo(u.y);v[3]=bfhi(u.y);
  v[4]=bflo(u.z);v[5]=bfhi(u.z);v[6]=bflo(u.w);v[7]=bfhi(u.w);
}
__device__ __forceinline__ void load4f(const float* p, float* v){
  float4 a = *(const float4*)p; v[0]=a.x;v[1]=a.y;v[2]=a.z;v[3]=a.w;
}
__device__ __forceinline__ void load4h(const u16* p, float* v){
  uint2 u = *(const uint2*)p;
  v[0]=bflo(u.x); v[1]=bfhi(u.x); v[2]=bflo(u.y); v[3]=bfhi(u.y);
}
__device__ __forceinline__ void store2bf(u16* p, float a, float b){
  *(u32*)p = pack2(a,b);
}
__device__ __forceinline__ void store4bf(u16* p, float a, float b, float c, float d){
  uint2 t; t.x = pack2(a,b); t.y = pack2(c,d);
  *(uint2*)p = t;
}

// ---------- misc: zero an int buffer ----------
__global__ __launch_bounds__(256) void zero_kernel(int* p, int n){
  int i = blockIdx.x*256 + threadIdx.x;
  if (i < n) p[i] = 0;
}

// ---------- GEMM: C[N,128](bf16) = A[N,128] @ W[128,128](fp32 global) ----------
// A is fp32 if Ah==0 else bf16. 32 rows/block, 256 thr.
__global__ __launch_bounds__(256) void gemm128_kernel(
    const float* __restrict__ Af, const u16* __restrict__ Ah,
    const float* __restrict__ W, u16* __restrict__ C, int N)
{
  __shared__ u16 Ws[128*128];
  __shared__ float As[32*128];
  const int tid = threadIdx.x;
  {
    const float4* Wv = (const float4*)W;
#pragma unroll
    for (int i = 0; i < 16; ++i) {
      float4 w = Wv[i*256 + tid];
      uint2 t; t.x = pack2(w.x,w.y); t.y = pack2(w.z,w.w);
      ((uint2*)Ws)[i*256 + tid] = t;
    }
  }
  const int rowBase = blockIdx.x * 32;
#pragma unroll
  for (int j = 0; j < 2; ++j) {
    int e = (j*256 + tid) * 8;
    int r = e >> 7, k = e & 127;
    int n = rowBase + r;
    float v[8];
    if (n < N) {
      if (Ah) load8h(Ah + (size_t)n*128 + k, v);
      else    load8f(Af + (size_t)n*128 + k, v);
    } else {
      for (int q=0;q<8;++q) v[q]=0.f;
    }
#pragma unroll
    for (int q=0;q<8;++q) As[r*128 + k + q] = v[q];
  }
  __syncthreads();

  const int c4 = (tid & 31) * 4;
  const int r0 = tid >> 5;
  float acc[4][4];
#pragma unroll
  for (int a=0;a<4;++a)
#pragma unroll
    for (int b=0;b<4;++b) acc[a][b]=0.f;

  for (int k = 0; k < 128; k += 4) {
    float wv[4][4];
#pragma unroll
    for (int kk=0;kk<4;++kk) {
      uint2 wu = *(const uint2*)&Ws[(k+kk)*128 + c4];
      wv[kk][0]=bflo(wu.x); wv[kk][1]=bfhi(wu.x); wv[kk][2]=bflo(wu.y); wv[kk][3]=bfhi(wu.y);
    }
#pragma unroll
    for (int ri=0;ri<4;++ri) {
      const float4 a4 = *(const float4*)&As[(r0 + ri*8)*128 + k];
      float av0=a4.x, av1=a4.y, av2=a4.z, av3=a4.w;
#pragma unroll
      for (int cc=0;cc<4;++cc) {
        float t = acc[ri][cc];
        t = fmaf(av0, wv[0][cc], t);
        t = fmaf(av1, wv[1][cc], t);
        t = fmaf(av2, wv[2][cc], t);
        t = fmaf(av3, wv[3][cc], t);
        acc[ri][cc] = t;
      }
    }
  }
#pragma unroll
  for (int ri=0;ri<4;++ri) {
    int n = rowBase + r0 + ri*8;
    if (n < N)
      store4bf(&C[(size_t)n*128 + c4], acc[ri][0],acc[ri][1],acc[ri][2],acc[ri][3]);
  }
}

// ---------- fused update: out = T + lrelu(Hy@latW) + prev ; S (+)= out ; opt store out ----------
// Prev is fp32 if PrevH==0 else bf16. initS: S = prev+out, else S += out.
__global__ __launch_bounds__(256) void update_kernel(
    const u16* __restrict__ T, const u16* __restrict__ Hy,
    const float* __restrict__ latW,
    const float* __restrict__ PrevF, const u16* __restrict__ PrevH,
    u16* __restrict__ Pout, float* __restrict__ S, int N, int initS)
{
  __shared__ u16 Ws[128*128];
  __shared__ float As[32*128];
  const int tid = threadIdx.x;
  {
    const float4* Wv = (const float4*)latW;
#pragma unroll
    for (int i = 0; i < 16; ++i) {
      float4 w = Wv[i*256 + tid];
      uint2 t; t.x = pack2(w.x,w.y); t.y = pack2(w.z,w.w);
      ((uint2*)Ws)[i*256 + tid] = t;
    }
  }
  const int rowBase = blockIdx.x * 32;
#pragma unroll
  for (int j = 0; j < 2; ++j) {
    int e = (j*256 + tid) * 8;
    int r = e >> 7, k = e & 127;
    int n = rowBase + r;
    float v[8];
    if (n < N) load8h(Hy + (size_t)n*128 + k, v);
    else { for (int q=0;q<8;++q) v[q]=0.f; }
#pragma unroll
    for (int q=0;q<8;++q) As[r*128 + k + q] = v[q];
  }
  __syncthreads();

  const int c4 = (tid & 31) * 4;
  const int r0 = tid >> 5;
  float acc[4][4];
#pragma unroll
  for (int a=0;a<4;++a)
#pragma unroll
    for (int b=0;b<4;++b) acc[a][b]=0.f;

  for (int k = 0; k < 128; k += 4) {
    float wv[4][4];
#pragma unroll
    for (int kk=0;kk<4;++kk) {
      uint2 wu = *(const uint2*)&Ws[(k+kk)*128 + c4];
      wv[kk][0]=bflo(wu.x); wv[kk][1]=bfhi(wu.x); wv[kk][2]=bflo(wu.y); wv[kk][3]=bfhi(wu.y);
    }
#pragma unroll
    for (int ri=0;ri<4;++ri) {
      const float4 a4 = *(const float4*)&As[(r0 + ri*8)*128 + k];
      float av0=a4.x, av1=a4.y, av2=a4.z, av3=a4.w;
#pragma unroll
      for (int cc=0;cc<4;++cc) {
        float t = acc[ri][cc];
        t = fmaf(av0, wv[0][cc], t);
        t = fmaf(av1, wv[1][cc], t);
        t = fmaf(av2, wv[2][cc], t);
        t = fmaf(av3, wv[3][cc], t);
        acc[ri][cc] = t;
      }
    }
  }
#pragma unroll
  for (int ri=0;ri<4;++ri) {
    int n = rowBase + r0 + ri*8;
    if (n >= N) continue;
    size_t off = (size_t)n*128 + c4;
    float tv[4], pv[4], ov[4];
    load4h(T + off, tv);
    if (PrevH) load4h(PrevH + off, pv);
    else       load4f(PrevF + off, pv);
#pragma unroll
    for (int cc=0;cc<4;++cc) {
      float x = acc[ri][cc];
      float g = x > 0.f ? x : LEAKY*x;   // lrelu(Hy@latW)
      ov[cc] = g + tv[cc] + pv[cc];
    }
    if (Pout)
      store4bf(&Pout[off], ov[0],ov[1],ov[2],ov[3]);
    if (initS) {
      float4 s; s.x=pv[0]+ov[0]; s.y=pv[1]+ov[1]; s.z=pv[2]+ov[2]; s.w=pv[3]+ov[3];
      *(float4*)&S[off] = s;
    } else {
      float4 s = *(const float4*)&S[off];
      s.x += ov[0]; s.y += ov[1]; s.z += ov[2]; s.w += ov[3];
      *(float4*)&S[off] = s;
    }
  }
}

// ---------- hyper reduce: partial[b] = Hy_chunk^T @ Lat_chunk (chunk = 256 rows) ----------
// Lat is fp32 if L*h==0 else bf16 (per side).
__global__ __launch_bounds__(256) void reduce_kernel(
    const u16* __restrict__ HyU, const u16* __restrict__ HyI,
    const float* __restrict__ LatUf, const u16* __restrict__ LatUh,
    const float* __restrict__ LatIf, const u16* __restrict__ LatIh,
    u16* __restrict__ part, int Nu, int Ni, int nbU)
{
  __shared__ float Hs[32*128];
  __shared__ float Ls[32*128];
  const int b = blockIdx.x;
  const u16* Hy; const float* Lf; const u16* Lh; int N, cstart;
  if (b < nbU) { Hy=HyU; Lf=LatUf; Lh=LatUh; N=Nu; cstart = b*256; }
  else         { Hy=HyI; Lf=LatIf; Lh=LatIh; N=Ni; cstart = (b-nbU)*256; }
  const int cend = (N < cstart+256) ? N : (cstart+256);
  const int tid = threadIdx.x;
  const int ty = tid >> 4, tx = tid & 15;
  const int h0 = ty*8;
  const int dA = tx*4, dB = tx*4+64;
  float acc[8][8];
#pragma unroll
  for (int a=0;a<8;++a)
#pragma unroll
    for (int c=0;c<8;++c) acc[a][c]=0.f;

  for (int t0 = cstart; t0 < cend; t0 += 32) {
#pragma unroll
    for (int j=0;j<2;++j) {
      int e = (j*256+tid)*8;
      int r = e>>7, k = e&127;
      int n = t0 + r;
      float v[8], u[8];
      if (n < cend) {
        load8h(Hy + (size_t)n*128+k, v);
        if (Lh) load8h(Lh + (size_t)n*128+k, u);
        else    load8f(Lf + (size_t)n*128+k, u);
      } else {
        for (int q=0;q<8;++q){v[q]=0.f;u[q]=0.f;}
      }
#pragma unroll
      for (int q=0;q<8;++q){ Hs[r*128+k+q]=v[q]; Ls[r*128+k+q]=u[q]; }
    }
    __syncthreads();
    for (int k=0;k<32;++k) {
      float4 hA = *(const float4*)&Hs[k*128+h0];
      float4 hB = *(const float4*)&Hs[k*128+h0+4];
      float4 lA = *(const float4*)&Ls[k*128+dA];
      float4 lB = *(const float4*)&Ls[k*128+dB];
      float hv[8]; float lv[8];
      hv[0]=hA.x;hv[1]=hA.y;hv[2]=hA.z;hv[3]=hA.w;hv[4]=hB.x;hv[5]=hB.y;hv[6]=hB.z;hv[7]=hB.w;
      lv[0]=lA.x;lv[1]=lA.y;lv[2]=lA.z;lv[3]=lA.w;lv[4]=lB.x;lv[5]=lB.y;lv[6]=lB.z;lv[7]=lB.w;
#pragma unroll
      for (int a=0;a<8;++a)
#pragma unroll
        for (int c=0;c<8;++c)
          acc[a][c] = fmaf(hv[a], lv[c], acc[a][c]);
    }
    __syncthreads();
  }
  u16* pb = part + (size_t)b*16384;
#pragma unroll
  for (int a=0;a<8;++a) {
    int h = h0+a;
    store4bf(&pb[h*128+dA], acc[a][0],acc[a][1],acc[a][2],acc[a][3]);
    store4bf(&pb[h*128+dB], acc[a][4],acc[a][5],acc[a][6],acc[a][7]);
  }
}

__global__ __launch_bounds__(256) void reduce2_kernel(
    const u16* __restrict__ part, float* __restrict__ Ru, float* __restrict__ Ri,
    int nbU, int nbI)
{
  const int e = blockIdx.x*256 + threadIdx.x;   // 0..16383
  const int side = blockIdx.y;
  const u16* p = part + (side ? (size_t)nbU*16384 : 0) + e;
  const int nb = side ? nbI : nbU;
  float s = 0.f;
  for (int j=0;j<nb;++j) s += bf2f(p[(size_t)j*16384]);
  if (side) Ri[e] = s; else Ru[e] = s;
}

// ---------- FC chain: per-column independent; lat=lrelu(R); 3x residual relu FC ----------
__global__ __launch_bounds__(128) void fc_kernel(
    const float* __restrict__ Ru, const float* __restrict__ Ri,
    const float* __restrict__ W3u, const float* __restrict__ W3i,
    float* __restrict__ latU, float* __restrict__ latI)
{
  __shared__ float cur[128];
  const int h = threadIdx.x;
  const int d = blockIdx.x;
  const int side = blockIdx.y;
  const float* R  = side ? Ri  : Ru;
  const float* W3 = side ? W3i : W3u;
  float* lat      = side ? latI : latU;
  float x = R[h*128 + d];
  cur[h] = x > 0.f ? x : LEAKY*x;
  __syncthreads();
  for (int s=0;s<3;++s) {
    const float* w = W3 + s*16384 + h;
    float val = 0.f;
#pragma unroll 8
    for (int hp=0; hp<128; ++hp) val = fmaf(cur[hp], w[hp*128], val);
    val = (val > 0.f ? val : 0.f) + cur[h];
    __syncthreads();
    cur[h] = val;
    __syncthreads();
  }
  lat[h*128+d] = cur[h];
}

// ---------- CSR-based SpMM: T[row,:] = relu( sum_e val_e * Y[idx_e,:] ) ----------
// Defensive: edge range clamped to [0,E], gather row clamped to [0,Ncol).
__global__ __launch_bounds__(256) void spmm_kernel(
    const uint2* __restrict__ csr, const int* __restrict__ rowptr,
    const u16* __restrict__ Y, u16* __restrict__ T, int N, int Ncol, int E)
{
  const int lane = threadIdx.x & 63;
  const int row = blockIdx.x*4 + (threadIdx.x >> 6);
  if (row >= N) return;
  int e  = rowptr[row];
  int e1 = rowptr[row+1];
  if (e < 0) e = 0;
  if (e > E) e = E;
  if (e1 < e) e1 = e;
  if (e1 > E) e1 = E;
  const u32 cmax = (u32)(Ncol - 1);
  float a0=0.f, a1=0.f;
  const int c2 = lane*2;
  for (; e+2 <= e1; e += 2) {
    uint2 p0 = csr[e], p1 = csr[e+1];
    u32 i0 = p0.x < cmax ? p0.x : cmax;
    u32 i1 = p1.x < cmax ? p1.x : cmax;
    u32 y0 = *(const u32*)&Y[(size_t)i0*128 + c2];
    u32 y1 = *(const u32*)&Y[(size_t)i1*128 + c2];
    float v0 = __uint_as_float(p0.y), v1 = __uint_as_float(p1.y);
    a0 = fmaf(v0, bflo(y0), a0); a1 = fmaf(v0, bfhi(y0), a1);
    a0 = fmaf(v1, bflo(y1), a0); a1 = fmaf(v1, bfhi(y1), a1);
  }
  if (e < e1) {
    uint2 p0 = csr[e];
    u32 i0 = p0.x < cmax ? p0.x : cmax;
    u32 y0 = *(const u32*)&Y[(size_t)i0*128 + c2];
    float v0 = __uint_as_float(p0.y);
    a0 = fmaf(v0, bflo(y0), a0); a1 = fmaf(v0, bfhi(y0), a1);
  }
  store2bf(&T[(size_t)row*128 + c2], a0 > 0.f ? a0 : 0.f, a1 > 0.f ? a1 : 0.f);
}

// ---------- CSR build ----------
__global__ __launch_bounds__(256) void hist_kernel(
    const int* __restrict__ rows, const int* __restrict__ cols,
    int* cntU, int* cntI, int E, int Nu, int Ni)
{
  int e = blockIdx.x*256 + threadIdx.x;
  if (e < E) {
    int r = rows[e], c = cols[e];
    if ((unsigned)r < (unsigned)Nu) atomicAdd(&cntU[r],1);
    if ((unsigned)c < (unsigned)Ni) atomicAdd(&cntI[c],1);
  }
}

__global__ __launch_bounds__(256) void scan_local_kernel(
    const int* __restrict__ cntU, const int* __restrict__ cntI,
    int* rpU, int* rpI, int* bsU, int* bsI, int Nu, int Ni)
{
  const int side = blockIdx.y;
  const int Nn = side ? Ni : Nu;
  const int* cnt = side ? cntI : cntU;
  int* rp = side ? rpI : rpU;
  int* bs = side ? bsI : bsU;
  const int nb = (Nn + 4095) >> 12;
  if ((int)blockIdx.x >= nb) return;
  __shared__ int sa[256], sb[256];
  const int tid = threadIdx.x;
  const int base = blockIdx.x*4096 + tid*16;
  int v[16]; int sum = 0;
#pragma unroll
  for (int q=0;q<16;++q){ int idx = base+q; int x = (idx<Nn)?cnt[idx]:0; v[q]=x; sum+=x; }
  sa[tid] = sum; __syncthreads();
  int* src = sa; int* dst = sb;
  for (int off=1; off<256; off<<=1) {
    int x = src[tid] + ((tid>=off) ? src[tid-off] : 0);
    dst[tid] = x;
    __syncthreads();
    int* t = src; src = dst; dst = t;
  }
  const int incl = src[tid];
  int run = incl - sum;  // exclusive
#pragma unroll
  for (int q=0;q<16;++q){ int idx=base+q; if (idx<Nn) rp[idx]=run; run+=v[q]; }
  if (tid==255) bs[blockIdx.x] = incl;
}

__global__ void scan_blocks_kernel(int* bsU, int* bsI, int* rpU, int* rpI, int Nu, int Ni)
{
  if (threadIdx.x != 0) return;
  const int side = blockIdx.y;
  int* bs = side?bsI:bsU; int* rp = side?rpI:rpU;
  const int Nn = side?Ni:Nu;
  const int nb = (Nn+4095)>>12;
  int run = 0;
  for (int b=0;b<nb;++b){ int t=bs[b]; bs[b]=run; run+=t; }
  rp[Nn] = run;
}

__global__ __launch_bounds__(256) void scan_add_kernel(
    const int* bsU, const int* bsI, int* rpU, int* rpI, int Nu, int Ni)
{
  const int side = blockIdx.y;
  const int Nn = side?Ni:Nu;
  const int* bs = side?bsI:bsU;
  int* rp = side?rpI:rpU;
  const int nb = (Nn+4095)>>12;
  if ((int)blockIdx.x >= nb) return;
  const int add = bs[blockIdx.x];
  const int base = blockIdx.x*4096 + threadIdx.x*16;
#pragma unroll
  for (int q=0;q<16;++q){ int idx=base+q; if (idx<Nn) rp[idx]+=add; }
}

__global__ __launch_bounds__(256) void scatter_kernel(
    const int* __restrict__ rows, const int* __restrict__ cols, const float* __restrict__ vals,
    const int* __restrict__ rpU, const int* __restrict__ rpI,
    int* curU, int* curI, uint2* csrU, uint2* csrI, int E, int Nu, int Ni)
{
  int e = blockIdx.x*256 + threadIdx.x;
  if (e >= E) return;
  int r = rows[e], c = cols[e];
  u32 vb = __float_as_uint(vals[e]);
  if ((unsigned)r < (unsigned)Nu && (unsigned)c < (unsigned)Ni) {
    int su = rpU[r] + atomicAdd(&curU[r], 1);
    if ((unsigned)su < (unsigned)E) { uint2 t; t.x=(u32)c; t.y=vb; csrU[su]=t; }
    int si = rpI[c] + atomicAdd(&curI[c], 1);
    if ((unsigned)si < (unsigned)E) { uint2 t; t.x=(u32)r; t.y=vb; csrI[si]=t; }
  }
}

// ---------- host ----------
extern "C" void kernel_launch(void* const* d_in, const int* in_sizes, int n_in,
                              void* d_out, int out_size, void* d_ws, size_t ws_size,
                              hipStream_t stream)
{
  const float* uE     = (const float*)d_in[0];
  const float* iE     = (const float*)d_in[1];
  const float* uhyper = (const float*)d_in[2];
  const float* ihyper = (const float*)d_in[3];
  const float* vals   = (const float*)d_in[4];
  const float* WhU    = (const float*)d_in[5];  // [L,3,128,128]
  const float* WhI    = (const float*)d_in[6];
  const float* WgU    = (const float*)d_in[7];  // [L,128,128]
  const float* WgI    = (const float*)d_in[8];
  const int*   rows   = (const int*)d_in[9];
  const int*   cols   = (const int*)d_in[10];
  const int U = in_sizes[0]/128;
  const int I = in_sizes[1]/128;
  const int E = in_sizes[4];
  const int L = in_sizes[7]/(128*128);
  (void)n_in; (void)out_size;

  float* Su = (float*)d_out;
  float* Si = Su + (size_t)U*128;

  char* p = (char*)d_ws;
  char* base0 = p;
  // bump allocator, 256B aligned
  u16* uuH; u16* iiH; u16* PU; u16* PI; u16* YU; u16* TU; u16* pool3;
  uint2* csrU; uint2* csrI; int* rpU; int* rpI; int* cntU; int* cntI;
  int* bsU; int* bsI; float* Ru; float* Ri; float* latU; float* latI;
  {
    size_t off = 0;
    #define ALLOC(var, type, bytes) var = (type)(base0 + off); off = (off + (bytes) + 255) & ~(size_t)255;
    ALLOC(uuH,  u16*, (size_t)U*128*2)
    ALLOC(iiH,  u16*, (size_t)I*128*2)
    ALLOC(PU,   u16*, (size_t)U*128*2)
    ALLOC(PI,   u16*, (size_t)I*128*2)
    ALLOC(YU,   u16*, (size_t)U*128*2)      // Y_U; later reused as reduce partials
    ALLOC(TU,   u16*, (size_t)U*128*2)
    ALLOC(pool3,u16*, (size_t)I*128*2)      // Y_I then T_I
    ALLOC(csrU, uint2*, (size_t)E*8)
    ALLOC(csrI, uint2*, (size_t)E*8)
    ALLOC(rpU,  int*, (size_t)(U+1)*4)
    ALLOC(rpI,  int*, (size_t)(I+1)*4)
    ALLOC(cntU, int*, (size_t)U*4)
    ALLOC(cntI, int*, (size_t)I*4)
    ALLOC(bsU,  int*, 64*4)
    ALLOC(bsI,  int*, 64*4)
    ALLOC(Ru,   float*, 16384*4)
    ALLOC(Ri,   float*, 16384*4)
    ALLOC(latU, float*, 16384*4)
    ALLOC(latI, float*, 16384*4)
    #undef ALLOC
    // ws_size guard: bail out cleanly (deterministic -> graph-safe) rather
    // than fault the GPU if the harness workspace is too small.
    if (off > ws_size) return;
  }
  const int cntN = (int)(((size_t)((char*)bsU - (char*)cntU)) / 4);

  const int nbU = (U+4095)>>12, nbI = (I+4095)>>12;
  const int nbMax = nbU > nbI ? nbU : nbI;
  const int rbU = (U+255)>>8, rbI = (I+255)>>8;   // reduce chunks (256 rows)

  // --- CSR build (both directions) ---
  zero_kernel<<<(cntN+255)/256, 256, 0, stream>>>(cntU, cntN);
  hist_kernel<<<(E+255)/256, 256, 0, stream>>>(rows, cols, cntU, cntI, E, U, I);
  scan_local_kernel<<<dim3(nbMax,2), 256, 0, stream>>>(cntU,cntI,rpU,rpI,bsU,bsI,U,I);
  scan_blocks_kernel<<<dim3(1,2), 64, 0, stream>>>(bsU,bsI,rpU,rpI,U,I);
  scan_add_kernel<<<dim3(nbMax,2), 256, 0, stream>>>(bsU,bsI,rpU,rpI,U,I);
  zero_kernel<<<(cntN+255)/256, 256, 0, stream>>>(cntU, cntN);
  scatter_kernel<<<(E+255)/256, 256, 0, stream>>>(rows,cols,vals,rpU,rpI,cntU,cntI,csrU,csrI,E,U,I);

  // --- hyper embeddings ---
  gemm128_kernel<<<(U+31)/32, 256, 0, stream>>>(uE, (const u16*)0, uhyper, uuH, U);
  gemm128_kernel<<<(I+31)/32, 256, 0, stream>>>(iE, (const u16*)0, ihyper, iiH, I);

  for (int l=0; l<L; ++l) {
    const float* wgu = WgU + (size_t)l*16384;
    const float* wgi = WgI + (size_t)l*16384;
    const float* whu = WhU + (size_t)l*3*16384;
    const float* whi = WhI + (size_t)l*3*16384;
    const bool last = (l == L-1);
    if (l == 0) {
      gemm128_kernel<<<(I+31)/32, 256, 0, stream>>>(iE, (const u16*)0, wgu, pool3, I); // Y_I = iE@WgU
      spmm_kernel<<<(U+3)/4, 256, 0, stream>>>(csrU, rpU, pool3, TU, U, I, E);         // T_U = relu(adj@Y_I)
      gemm128_kernel<<<(U+31)/32, 256, 0, stream>>>(uE, (const u16*)0, wgi, YU, U);    // Y_U = uE@WgI
      spmm_kernel<<<(I+3)/4, 256, 0, stream>>>(csrI, rpI, YU, pool3, I, U, E);         // T_I = relu(adjT@Y_U)
      reduce_kernel<<<rbU+rbI, 256, 0, stream>>>(uuH,iiH, uE,(const u16*)0, iE,(const u16*)0, YU,U,I,rbU);
      reduce2_kernel<<<dim3(64,2), 256, 0, stream>>>(YU, Ru, Ri, rbU, rbI);
      fc_kernel<<<dim3(128,2), 128, 0, stream>>>(Ru,Ri,whu,whi,latU,latI);
      update_kernel<<<(U+31)/32, 256, 0, stream>>>(TU,    uuH, latU, uE, (const u16*)0, PU, Su, U, 1);
      update_kernel<<<(I+31)/32, 256, 0, stream>>>(pool3, iiH, latI, iE, (const u16*)0, PI, Si, I, 1);
    } else {
      gemm128_kernel<<<(I+31)/32, 256, 0, stream>>>((const float*)0, PI, wgu, pool3, I);
      spmm_kernel<<<(U+3)/4, 256, 0, stream>>>(csrU, rpU, pool3, TU, U, I, E);
      gemm128_kernel<<<(U+31)/32, 256, 0, stream>>>((const float*)0, PU, wgi, YU, U);
      spmm_kernel<<<(I+3)/4, 256, 0, stream>>>(csrI, rpI, YU, pool3, I, U, E);
      reduce_kernel<<<rbU+rbI, 256, 0, stream>>>(uuH,iiH, (const float*)0,PU, (const float*)0,PI, YU,U,I,rbU);
      reduce2_kernel<<<dim3(64,2), 256, 0, stream>>>(YU, Ru, Ri, rbU, rbI);
      fc_kernel<<<dim3(128,2), 128, 0, stream>>>(Ru,Ri,whu,whi,latU,latI);
      update_kernel<<<(U+31)/32, 256, 0, stream>>>(TU,    uuH, latU, (const float*)0, PU, last?(u16*)0:PU, Su, U, 0);
      update_kernel<<<(I+31)/32, 256, 0, stream>>>(pool3, iiH, latI, (const float*)0, PI, last?(u16*)0:PI, Si, I, 0);
    }
  }
}

// Round 5
// 1391.317 us; speedup vs baseline: 1.1694x; 1.1694x over previous
//
#include <hip/hip_runtime.h>
#include <stdint.h>

#define LEAKY 0.1f
typedef unsigned short u16;
typedef unsigned int u32;
typedef short bf16x8 __attribute__((ext_vector_type(8)));
typedef float f32x4 __attribute__((ext_vector_type(4)));

// ---------- bf16 helpers (storage = ushort) ----------
__device__ __forceinline__ float bflo(u32 u){ union{u32 i; float f;} c; c.i = u<<16; return c.f; }
__device__ __forceinline__ float bfhi(u32 u){ union{u32 i; float f;} c; c.i = u & 0xffff0000u; return c.f; }
__device__ __forceinline__ float bf2f(u16 v){ union{u32 i; float f;} c; c.i = ((u32)v)<<16; return c.f; }
__device__ __forceinline__ u16 f2bf(float f){
  union{float f; u32 i;} c; c.f = f;
  u32 r = (c.i + 0x7fffu + ((c.i>>16)&1u)) >> 16;
  return (u16)r;
}
__device__ __forceinline__ u32 pack2(float a, float b){ return (u32)f2bf(a) | ((u32)f2bf(b)<<16); }

__device__ __forceinline__ void load8f(const float* p, float* v){
  const float4* q = (const float4*)p; float4 a = q[0], b = q[1];
  v[0]=a.x;v[1]=a.y;v[2]=a.z;v[3]=a.w;v[4]=b.x;v[5]=b.y;v[6]=b.z;v[7]=b.w;
}
__device__ __forceinline__ void load8h(const u16* p, float* v){
  uint4 u = *(const uint4*)p;
  v[0]=bflo(u.x);v[1]=bfhi(u.x);v[2]=bflo(u.y);v[3]=bfhi(u.y);
  v[4]=bflo(u.z);v[5]=bfhi(u.z);v[6]=bflo(u.w);v[7]=bfhi(u.w);
}
__device__ __forceinline__ void load4f(const float* p, float* v){
  float4 a = *(const float4*)p; v[0]=a.x;v[1]=a.y;v[2]=a.z;v[3]=a.w;
}
__device__ __forceinline__ void load4h(const u16* p, float* v){
  uint2 u = *(const uint2*)p;
  v[0]=bflo(u.x); v[1]=bfhi(u.x); v[2]=bflo(u.y); v[3]=bfhi(u.y);
}
__device__ __forceinline__ void store2bf(u16* p, float a, float b){
  *(u32*)p = pack2(a,b);
}
__device__ __forceinline__ void store4bf(u16* p, float a, float b, float c, float d){
  uint2 t; t.x = pack2(a,b); t.y = pack2(c,d);
  *(uint2*)p = t;
}

// ---------- misc: zero an int buffer ----------
__global__ __launch_bounds__(256) void zero_kernel(int* p, int n){
  int i = blockIdx.x*256 + threadIdx.x;
  if (i < n) p[i] = 0;
}

// ---------- stage W[128][128] fp32 -> LDS transposed bf16 Wt[n][k], stride 136 ----------
__device__ __forceinline__ void stageWt(const float* __restrict__ W, u16* Wt, int tid){
  const int n = tid & 127, khalf = tid >> 7;
#pragma unroll
  for (int g = 0; g < 16; ++g) {
    int k0 = khalf*64 + g*4;
    float w0 = W[(k0+0)*128 + n];
    float w1 = W[(k0+1)*128 + n];
    float w2 = W[(k0+2)*128 + n];
    float w3 = W[(k0+3)*128 + n];
    uint2 t; t.x = pack2(w0,w1); t.y = pack2(w2,w3);
    *(uint2*)&Wt[n*136 + k0] = t;
  }
}

// ---------- MFMA GEMM: C[N,128](bf16) = A[N,128] @ W[128,128](fp32 global) ----------
// A fp32 if Ah==0 else bf16. 64 rows/block, 256 thr = 4 waves x 16-row strip.
// Layouts (16x16x32 bf16): A[m=lane&15][k=quad*8+j], B[k=quad*8+j][n=lane&15],
// D[row=quad*4+reg][col=lane&15].
__global__ __launch_bounds__(256) void gemm128_kernel(
    const float* __restrict__ Af, const u16* __restrict__ Ah,
    const float* __restrict__ W, u16* __restrict__ C, int N)
{
  __shared__ alignas(16) u16 Wt[128*136];
  const int tid = threadIdx.x;
  stageWt(W, Wt, tid);
  __syncthreads();

  const int w = tid >> 6, lane = tid & 63;
  const int m = lane & 15, quad = lane >> 4;
  const int rowBase = blockIdx.x*64 + w*16;
  int arow = rowBase + m;
  if (arow >= N) arow = N-1;

  bf16x8 af[4];
  if (Ah) {
#pragma unroll
    for (int kt=0; kt<4; ++kt)
      af[kt] = *(const bf16x8*)(Ah + (size_t)arow*128 + kt*32 + quad*8);
  } else {
#pragma unroll
    for (int kt=0; kt<4; ++kt) {
      float v[8]; load8f(Af + (size_t)arow*128 + kt*32 + quad*8, v);
      bf16x8 t;
#pragma unroll
      for (int j=0;j<8;++j) t[j] = (short)f2bf(v[j]);
      af[kt] = t;
    }
  }

#pragma unroll
  for (int jt=0; jt<8; ++jt) {
    f32x4 acc = {0.f,0.f,0.f,0.f};
#pragma unroll
    for (int kt=0; kt<4; ++kt) {
      bf16x8 bf = *(const bf16x8*)&Wt[(jt*16+m)*136 + kt*32 + quad*8];
      acc = __builtin_amdgcn_mfma_f32_16x16x32_bf16(af[kt], bf, acc, 0, 0, 0);
    }
    const int col = jt*16 + m;
#pragma unroll
    for (int r=0;r<4;++r) {
      int rg = rowBase + quad*4 + r;
      if (rg < N) C[(size_t)rg*128 + col] = f2bf(acc[r]);
    }
  }
}

// ---------- fused update (MFMA): out = T + lrelu(Hy@latW) + prev ; S (+)= out ----------
// 64 rows/block. Prev fp32 if PrevH==0 else bf16. initS: S = prev+out else S += out.
__global__ __launch_bounds__(256) void update_kernel(
    const u16* __restrict__ T, const u16* __restrict__ Hy,
    const float* __restrict__ latW,
    const float* __restrict__ PrevF, const u16* __restrict__ PrevH,
    u16* __restrict__ Pout, float* __restrict__ S, int N, int initS)
{
  __shared__ alignas(16) char shmem[34816];  // union: Wt u16[128*136] | Gs f32[64*132]
  u16* Wt = (u16*)shmem;
  float* Gs = (float*)shmem;
  const int tid = threadIdx.x;
  stageWt(latW, Wt, tid);
  __syncthreads();

  const int w = tid >> 6, lane = tid & 63;
  const int m = lane & 15, quad = lane >> 4;
  const int rowBase = blockIdx.x*64;
  const int wrow = rowBase + w*16;
  int arow = wrow + m;
  if (arow >= N) arow = N-1;

  bf16x8 af[4];
#pragma unroll
  for (int kt=0; kt<4; ++kt)
    af[kt] = *(const bf16x8*)(Hy + (size_t)arow*128 + kt*32 + quad*8);

  f32x4 acc[8];
#pragma unroll
  for (int jt=0; jt<8; ++jt) {
    f32x4 a = {0.f,0.f,0.f,0.f};
#pragma unroll
    for (int kt=0; kt<4; ++kt) {
      bf16x8 bf = *(const bf16x8*)&Wt[(jt*16+m)*136 + kt*32 + quad*8];
      a = __builtin_amdgcn_mfma_f32_16x16x32_bf16(af[kt], bf, a, 0, 0, 0);
    }
    acc[jt] = a;
  }
  __syncthreads();   // all Wt reads done; reuse LDS as Gs
  // write lrelu(acc) -> Gs[64][132]
#pragma unroll
  for (int jt=0; jt<8; ++jt) {
#pragma unroll
    for (int r=0;r<4;++r) {
      float x = acc[jt][r];
      Gs[(w*16 + quad*4 + r)*132 + jt*16 + m] = x > 0.f ? x : LEAKY*x;
    }
  }
  __syncthreads();

  // vectorized epilogue over 64 rows
  const int c4 = (tid & 31) * 4;
  const int r0 = tid >> 5;
#pragma unroll
  for (int ri=0; ri<8; ++ri) {
    int lr = r0 + ri*8;           // 0..63
    int n = rowBase + lr;
    if (n >= N) continue;
    size_t off = (size_t)n*128 + c4;
    float gv[4]; load4f(&Gs[lr*132 + c4], gv);
    float tv[4], pv[4], ov[4];
    load4h(T + off, tv);
    if (PrevH) load4h(PrevH + off, pv);
    else       load4f(PrevF + off, pv);
#pragma unroll
    for (int cc=0;cc<4;++cc) ov[cc] = gv[cc] + tv[cc] + pv[cc];
    if (Pout)
      store4bf(&Pout[off], ov[0],ov[1],ov[2],ov[3]);
    if (initS) {
      float4 s; s.x=pv[0]+ov[0]; s.y=pv[1]+ov[1]; s.z=pv[2]+ov[2]; s.w=pv[3]+ov[3];
      *(float4*)&S[off] = s;
    } else {
      float4 s = *(const float4*)&S[off];
      s.x += ov[0]; s.y += ov[1]; s.z += ov[2]; s.w += ov[3];
      *(float4*)&S[off] = s;
    }
  }
}

// ---------- hyper reduce: partial[b] = Hy_chunk^T @ Lat_chunk (chunk = 256 rows) ----------
__global__ __launch_bounds__(256) void reduce_kernel(
    const u16* __restrict__ HyU, const u16* __restrict__ HyI,
    const float* __restrict__ LatUf, const u16* __restrict__ LatUh,
    const float* __restrict__ LatIf, const u16* __restrict__ LatIh,
    u16* __restrict__ part, int Nu, int Ni, int nbU)
{
  __shared__ float Hs[32*128];
  __shared__ float Ls[32*128];
  const int b = blockIdx.x;
  const u16* Hy; const float* Lf; const u16* Lh; int N, cstart;
  if (b < nbU) { Hy=HyU; Lf=LatUf; Lh=LatUh; N=Nu; cstart = b*256; }
  else         { Hy=HyI; Lf=LatIf; Lh=LatIh; N=Ni; cstart = (b-nbU)*256; }
  const int cend = (N < cstart+256) ? N : (cstart+256);
  const int tid = threadIdx.x;
  const int ty = tid >> 4, tx = tid & 15;
  const int h0 = ty*8;
  const int dA = tx*4, dB = tx*4+64;
  float acc[8][8];
#pragma unroll
  for (int a=0;a<8;++a)
#pragma unroll
    for (int c=0;c<8;++c) acc[a][c]=0.f;

  for (int t0 = cstart; t0 < cend; t0 += 32) {
#pragma unroll
    for (int j=0;j<2;++j) {
      int e = (j*256+tid)*8;
      int r = e>>7, k = e&127;
      int n = t0 + r;
      float v[8], u[8];
      if (n < cend) {
        load8h(Hy + (size_t)n*128+k, v);
        if (Lh) load8h(Lh + (size_t)n*128+k, u);
        else    load8f(Lf + (size_t)n*128+k, u);
      } else {
        for (int q=0;q<8;++q){v[q]=0.f;u[q]=0.f;}
      }
#pragma unroll
      for (int q=0;q<8;++q){ Hs[r*128+k+q]=v[q]; Ls[r*128+k+q]=u[q]; }
    }
    __syncthreads();
    for (int k=0;k<32;++k) {
      float4 hA = *(const float4*)&Hs[k*128+h0];
      float4 hB = *(const float4*)&Hs[k*128+h0+4];
      float4 lA = *(const float4*)&Ls[k*128+dA];
      float4 lB = *(const float4*)&Ls[k*128+dB];
      float hv[8]; float lv[8];
      hv[0]=hA.x;hv[1]=hA.y;hv[2]=hA.z;hv[3]=hA.w;hv[4]=hB.x;hv[5]=hB.y;hv[6]=hB.z;hv[7]=hB.w;
      lv[0]=lA.x;lv[1]=lA.y;lv[2]=lA.z;lv[3]=lA.w;lv[4]=lB.x;lv[5]=lB.y;lv[6]=lB.z;lv[7]=lB.w;
#pragma unroll
      for (int a=0;a<8;++a)
#pragma unroll
        for (int c=0;c<8;++c)
          acc[a][c] = fmaf(hv[a], lv[c], acc[a][c]);
    }
    __syncthreads();
  }
  u16* pb = part + (size_t)b*16384;
#pragma unroll
  for (int a=0;a<8;++a) {
    int h = h0+a;
    store4bf(&pb[h*128+dA], acc[a][0],acc[a][1],acc[a][2],acc[a][3]);
    store4bf(&pb[h*128+dB], acc[a][4],acc[a][5],acc[a][6],acc[a][7]);
  }
}

__global__ __launch_bounds__(256) void reduce2_kernel(
    const u16* __restrict__ part, float* __restrict__ Ru, float* __restrict__ Ri,
    int nbU, int nbI)
{
  const int e = blockIdx.x*256 + threadIdx.x;   // 0..16383
  const int side = blockIdx.y;
  const u16* p = part + (side ? (size_t)nbU*16384 : 0) + e;
  const int nb = side ? nbI : nbU;
  float s = 0.f;
  for (int j=0;j<nb;++j) s += bf2f(p[(size_t)j*16384]);
  if (side) Ri[e] = s; else Ru[e] = s;
}

// ---------- FC chain: per-column independent; lat=lrelu(R); 3x residual relu FC ----------
__global__ __launch_bounds__(128) void fc_kernel(
    const float* __restrict__ Ru, const float* __restrict__ Ri,
    const float* __restrict__ W3u, const float* __restrict__ W3i,
    float* __restrict__ latU, float* __restrict__ latI)
{
  __shared__ float cur[128];
  const int h = threadIdx.x;
  const int d = blockIdx.x;
  const int side = blockIdx.y;
  const float* R  = side ? Ri  : Ru;
  const float* W3 = side ? W3i : W3u;
  float* lat      = side ? latI : latU;
  float x = R[h*128 + d];
  cur[h] = x > 0.f ? x : LEAKY*x;
  __syncthreads();
  for (int s=0;s<3;++s) {
    const float* w = W3 + s*16384 + h;
    float val = 0.f;
#pragma unroll 8
    for (int hp=0; hp<128; ++hp) val = fmaf(cur[hp], w[hp*128], val);
    val = (val > 0.f ? val : 0.f) + cur[h];
    __syncthreads();
    cur[h] = val;
    __syncthreads();
  }
  lat[h*128+d] = cur[h];
}

// ---------- CSR-based SpMM: T[row,:] = relu( sum_e val_e * Y[idx_e,:] ) ----------
__global__ __launch_bounds__(256) void spmm_kernel(
    const uint2* __restrict__ csr, const int* __restrict__ rowptr,
    const u16* __restrict__ Y, u16* __restrict__ T, int N, int Ncol, int E)
{
  const int lane = threadIdx.x & 63;
  const int row = blockIdx.x*4 + (threadIdx.x >> 6);
  if (row >= N) return;
  int e  = rowptr[row];
  int e1 = rowptr[row+1];
  if (e < 0) e = 0;
  if (e > E) e = E;
  if (e1 < e) e1 = e;
  if (e1 > E) e1 = E;
  const u32 cmax = (u32)(Ncol - 1);
  float a0=0.f, a1=0.f;
  const int c2 = lane*2;
  for (; e+2 <= e1; e += 2) {
    uint2 p0 = csr[e], p1 = csr[e+1];
    u32 i0 = p0.x < cmax ? p0.x : cmax;
    u32 i1 = p1.x < cmax ? p1.x : cmax;
    u32 y0 = *(const u32*)&Y[(size_t)i0*128 + c2];
    u32 y1 = *(const u32*)&Y[(size_t)i1*128 + c2];
    float v0 = __uint_as_float(p0.y), v1 = __uint_as_float(p1.y);
    a0 = fmaf(v0, bflo(y0), a0); a1 = fmaf(v0, bfhi(y0), a1);
    a0 = fmaf(v1, bflo(y1), a0); a1 = fmaf(v1, bfhi(y1), a1);
  }
  if (e < e1) {
    uint2 p0 = csr[e];
    u32 i0 = p0.x < cmax ? p0.x : cmax;
    u32 y0 = *(const u32*)&Y[(size_t)i0*128 + c2];
    float v0 = __uint_as_float(p0.y);
    a0 = fmaf(v0, bflo(y0), a0); a1 = fmaf(v0, bfhi(y0), a1);
  }
  store2bf(&T[(size_t)row*128 + c2], a0 > 0.f ? a0 : 0.f, a1 > 0.f ? a1 : 0.f);
}

// ---------- CSR build ----------
__global__ __launch_bounds__(256) void hist_kernel(
    const int* __restrict__ rows, const int* __restrict__ cols,
    int* cntU, int* cntI, int E, int Nu, int Ni)
{
  int e = blockIdx.x*256 + threadIdx.x;
  if (e < E) {
    int r = rows[e], c = cols[e];
    if ((unsigned)r < (unsigned)Nu) atomicAdd(&cntU[r],1);
    if ((unsigned)c < (unsigned)Ni) atomicAdd(&cntI[c],1);
  }
}

__global__ __launch_bounds__(256) void scan_local_kernel(
    const int* __restrict__ cntU, const int* __restrict__ cntI,
    int* rpU, int* rpI, int* bsU, int* bsI, int Nu, int Ni)
{
  const int side = blockIdx.y;
  const int Nn = side ? Ni : Nu;
  const int* cnt = side ? cntI : cntU;
  int* rp = side ? rpI : rpU;
  int* bs = side ? bsI : bsU;
  const int nb = (Nn + 4095) >> 12;
  if ((int)blockIdx.x >= nb) return;
  __shared__ int sa[256], sb[256];
  const int tid = threadIdx.x;
  const int base = blockIdx.x*4096 + tid*16;
  int v[16]; int sum = 0;
#pragma unroll
  for (int q=0;q<16;++q){ int idx = base+q; int x = (idx<Nn)?cnt[idx]:0; v[q]=x; sum+=x; }
  sa[tid] = sum; __syncthreads();
  int* src = sa; int* dst = sb;
  for (int off=1; off<256; off<<=1) {
    int x = src[tid] + ((tid>=off) ? src[tid-off] : 0);
    dst[tid] = x;
    __syncthreads();
    int* t = src; src = dst; dst = t;
  }
  const int incl = src[tid];
  int run = incl - sum;  // exclusive
#pragma unroll
  for (int q=0;q<16;++q){ int idx=base+q; if (idx<Nn) rp[idx]=run; run+=v[q]; }
  if (tid==255) bs[blockIdx.x] = incl;
}

__global__ void scan_blocks_kernel(int* bsU, int* bsI, int* rpU, int* rpI, int Nu, int Ni)
{
  if (threadIdx.x != 0) return;
  const int side = blockIdx.y;
  int* bs = side?bsI:bsU; int* rp = side?rpI:rpU;
  const int Nn = side?Ni:Nu;
  const int nb = (Nn+4095)>>12;
  int run = 0;
  for (int b=0;b<nb;++b){ int t=bs[b]; bs[b]=run; run+=t; }
  rp[Nn] = run;
}

__global__ __launch_bounds__(256) void scan_add_kernel(
    const int* bsU, const int* bsI, int* rpU, int* rpI, int Nu, int Ni)
{
  const int side = blockIdx.y;
  const int Nn = side?Ni:Nu;
  const int* bs = side?bsI:bsU;
  int* rp = side?rpI:rpU;
  const int nb = (Nn+4095)>>12;
  if ((int)blockIdx.x >= nb) return;
  const int add = bs[blockIdx.x];
  const int base = blockIdx.x*4096 + threadIdx.x*16;
#pragma unroll
  for (int q=0;q<16;++q){ int idx=base+q; if (idx<Nn) rp[idx]+=add; }
}

__global__ __launch_bounds__(256) void scatter_kernel(
    const int* __restrict__ rows, const int* __restrict__ cols, const float* __restrict__ vals,
    const int* __restrict__ rpU, const int* __restrict__ rpI,
    int* curU, int* curI, uint2* csrU, uint2* csrI, int E, int Nu, int Ni)
{
  int e = blockIdx.x*256 + threadIdx.x;
  if (e >= E) return;
  int r = rows[e], c = cols[e];
  u32 vb = __float_as_uint(vals[e]);
  if ((unsigned)r < (unsigned)Nu && (unsigned)c < (unsigned)Ni) {
    int su = rpU[r] + atomicAdd(&curU[r], 1);
    if ((unsigned)su < (unsigned)E) { uint2 t; t.x=(u32)c; t.y=vb; csrU[su]=t; }
    int si = rpI[c] + atomicAdd(&curI[c], 1);
    if ((unsigned)si < (unsigned)E) { uint2 t; t.x=(u32)r; t.y=vb; csrI[si]=t; }
  }
}

// ---------- host ----------
extern "C" void kernel_launch(void* const* d_in, const int* in_sizes, int n_in,
                              void* d_out, int out_size, void* d_ws, size_t ws_size,
                              hipStream_t stream)
{
  const float* uE     = (const float*)d_in[0];
  const float* iE     = (const float*)d_in[1];
  const float* uhyper = (const float*)d_in[2];
  const float* ihyper = (const float*)d_in[3];
  const float* vals   = (const float*)d_in[4];
  const float* WhU    = (const float*)d_in[5];  // [L,3,128,128]
  const float* WhI    = (const float*)d_in[6];
  const float* WgU    = (const float*)d_in[7];  // [L,128,128]
  const float* WgI    = (const float*)d_in[8];
  const int*   rows   = (const int*)d_in[9];
  const int*   cols   = (const int*)d_in[10];
  const int U = in_sizes[0]/128;
  const int I = in_sizes[1]/128;
  const int E = in_sizes[4];
  const int L = in_sizes[7]/(128*128);
  (void)n_in; (void)out_size;

  float* Su = (float*)d_out;
  float* Si = Su + (size_t)U*128;

  char* base0 = (char*)d_ws;
  u16* uuH; u16* iiH; u16* PU; u16* PI; u16* YU; u16* TU; u16* pool3;
  uint2* csrU; uint2* csrI; int* rpU; int* rpI; int* cntU; int* cntI;
  int* bsU; int* bsI; float* Ru; float* Ri; float* latU; float* latI;
  {
    size_t off = 0;
    #define ALLOC(var, type, bytes) var = (type)(base0 + off); off = (off + (bytes) + 255) & ~(size_t)255;
    ALLOC(uuH,  u16*, (size_t)U*128*2)
    ALLOC(iiH,  u16*, (size_t)I*128*2)
    ALLOC(PU,   u16*, (size_t)U*128*2)
    ALLOC(PI,   u16*, (size_t)I*128*2)
    ALLOC(YU,   u16*, (size_t)U*128*2)      // Y_U; later reused as reduce partials
    ALLOC(TU,   u16*, (size_t)U*128*2)
    ALLOC(pool3,u16*, (size_t)I*128*2)      // Y_I then T_I
    ALLOC(csrU, uint2*, (size_t)E*8)
    ALLOC(csrI, uint2*, (size_t)E*8)
    ALLOC(rpU,  int*, (size_t)(U+1)*4)
    ALLOC(rpI,  int*, (size_t)(I+1)*4)
    ALLOC(cntU, int*, (size_t)U*4)
    ALLOC(cntI, int*, (size_t)I*4)
    ALLOC(bsU,  int*, 64*4)
    ALLOC(bsI,  int*, 64*4)
    ALLOC(Ru,   float*, 16384*4)
    ALLOC(Ri,   float*, 16384*4)
    ALLOC(latU, float*, 16384*4)
    ALLOC(latI, float*, 16384*4)
    #undef ALLOC
    if (off > ws_size) return;   // clean bail, graph-safe
  }
  const int cntN = (int)(((size_t)((char*)bsU - (char*)cntU)) / 4);

  const int nbU = (U+4095)>>12, nbI = (I+4095)>>12;
  const int nbMax = nbU > nbI ? nbU : nbI;
  const int rbU = (U+255)>>8, rbI = (I+255)>>8;   // reduce chunks (256 rows)
  const int gU = (U+63)/64, gI = (I+63)/64;        // MFMA gemm/update grids

  // --- CSR build (both directions) ---
  zero_kernel<<<(cntN+255)/256, 256, 0, stream>>>(cntU, cntN);
  hist_kernel<<<(E+255)/256, 256, 0, stream>>>(rows, cols, cntU, cntI, E, U, I);
  scan_local_kernel<<<dim3(nbMax,2), 256, 0, stream>>>(cntU,cntI,rpU,rpI,bsU,bsI,U,I);
  scan_blocks_kernel<<<dim3(1,2), 64, 0, stream>>>(bsU,bsI,rpU,rpI,U,I);
  scan_add_kernel<<<dim3(nbMax,2), 256, 0, stream>>>(bsU,bsI,rpU,rpI,U,I);
  zero_kernel<<<(cntN+255)/256, 256, 0, stream>>>(cntU, cntN);
  scatter_kernel<<<(E+255)/256, 256, 0, stream>>>(rows,cols,vals,rpU,rpI,cntU,cntI,csrU,csrI,E,U,I);

  // --- hyper embeddings ---
  gemm128_kernel<<<gU, 256, 0, stream>>>(uE, (const u16*)0, uhyper, uuH, U);
  gemm128_kernel<<<gI, 256, 0, stream>>>(iE, (const u16*)0, ihyper, iiH, I);

  for (int l=0; l<L; ++l) {
    const float* wgu = WgU + (size_t)l*16384;
    const float* wgi = WgI + (size_t)l*16384;
    const float* whu = WhU + (size_t)l*3*16384;
    const float* whi = WhI + (size_t)l*3*16384;
    const bool last = (l == L-1);
    if (l == 0) {
      gemm128_kernel<<<gI, 256, 0, stream>>>(iE, (const u16*)0, wgu, pool3, I);  // Y_I = iE@WgU
      spmm_kernel<<<(U+3)/4, 256, 0, stream>>>(csrU, rpU, pool3, TU, U, I, E);   // T_U = relu(adj@Y_I)
      gemm128_kernel<<<gU, 256, 0, stream>>>(uE, (const u16*)0, wgi, YU, U);     // Y_U = uE@WgI
      spmm_kernel<<<(I+3)/4, 256, 0, stream>>>(csrI, rpI, YU, pool3, I, U, E);   // T_I = relu(adjT@Y_U)
      reduce_kernel<<<rbU+rbI, 256, 0, stream>>>(uuH,iiH, uE,(const u16*)0, iE,(const u16*)0, YU,U,I,rbU);
      reduce2_kernel<<<dim3(64,2), 256, 0, stream>>>(YU, Ru, Ri, rbU, rbI);
      fc_kernel<<<dim3(128,2), 128, 0, stream>>>(Ru,Ri,whu,whi,latU,latI);
      update_kernel<<<gU, 256, 0, stream>>>(TU,    uuH, latU, uE, (const u16*)0, PU, Su, U, 1);
      update_kernel<<<gI, 256, 0, stream>>>(pool3, iiH, latI, iE, (const u16*)0, PI, Si, I, 1);
    } else {
      gemm128_kernel<<<gI, 256, 0, stream>>>((const float*)0, PI, wgu, pool3, I);
      spmm_kernel<<<(U+3)/4, 256, 0, stream>>>(csrU, rpU, pool3, TU, U, I, E);
      gemm128_kernel<<<gU, 256, 0, stream>>>((const float*)0, PU, wgi, YU, U);
      spmm_kernel<<<(I+3)/4, 256, 0, stream>>>(csrI, rpI, YU, pool3, I, U, E);
      reduce_kernel<<<rbU+rbI, 256, 0, stream>>>(uuH,iiH, (const float*)0,PU, (const float*)0,PI, YU,U,I,rbU);
      reduce2_kernel<<<dim3(64,2), 256, 0, stream>>>(YU, Ru, Ri, rbU, rbI);
      fc_kernel<<<dim3(128,2), 128, 0, stream>>>(Ru,Ri,whu,whi,latU,latI);
      update_kernel<<<gU, 256, 0, stream>>>(TU,    uuH, latU, (const float*)0, PU, last?(u16*)0:PU, Su, U, 0);
      update_kernel<<<gI, 256, 0, stream>>>(pool3, iiH, latI, (const float*)0, PI, last?(u16*)0:PI, Si, I, 0);
    }
  }
}

// Round 6
// 1285.779 us; speedup vs baseline: 1.2653x; 1.0821x over previous
//
#include <hip/hip_runtime.h>
#include <stdint.h>

#define LEAKY 0.1f
typedef unsigned short u16;
typedef unsigned int u32;
typedef short bf16x8 __attribute__((ext_vector_type(8)));
typedef float f32x4 __attribute__((ext_vector_type(4)));

// ---------- bf16 helpers (storage = ushort) ----------
__device__ __forceinline__ float bflo(u32 u){ union{u32 i; float f;} c; c.i = u<<16; return c.f; }
__device__ __forceinline__ float bfhi(u32 u){ union{u32 i; float f;} c; c.i = u & 0xffff0000u; return c.f; }
__device__ __forceinline__ float bf2f(u16 v){ union{u32 i; float f;} c; c.i = ((u32)v)<<16; return c.f; }
__device__ __forceinline__ u16 f2bf(float f){
  union{float f; u32 i;} c; c.f = f;
  u32 r = (c.i + 0x7fffu + ((c.i>>16)&1u)) >> 16;
  return (u16)r;
}
__device__ __forceinline__ u32 pack2(float a, float b){ return (u32)f2bf(a) | ((u32)f2bf(b)<<16); }

__device__ __forceinline__ void load8f(const float* p, float* v){
  const float4* q = (const float4*)p; float4 a = q[0], b = q[1];
  v[0]=a.x;v[1]=a.y;v[2]=a.z;v[3]=a.w;v[4]=b.x;v[5]=b.y;v[6]=b.z;v[7]=b.w;
}
__device__ __forceinline__ void load8h(const u16* p, float* v){
  uint4 u = *(const uint4*)p;
  v[0]=bflo(u.x);v[1]=bfhi(u.x);v[2]=bflo(u.y);v[3]=bfhi(u.y);
  v[4]=bflo(u.z);v[5]=bfhi(u.z);v[6]=bflo(u.w);v[7]=bfhi(u.w);
}
__device__ __forceinline__ void load4f(const float* p, float* v){
  float4 a = *(const float4*)p; v[0]=a.x;v[1]=a.y;v[2]=a.z;v[3]=a.w;
}
__device__ __forceinline__ void load4h(const u16* p, float* v){
  uint2 u = *(const uint2*)p;
  v[0]=bflo(u.x); v[1]=bfhi(u.x); v[2]=bflo(u.y); v[3]=bfhi(u.y);
}
__device__ __forceinline__ void store2bf(u16* p, float a, float b){
  *(u32*)p = pack2(a,b);
}
__device__ __forceinline__ void store4bf(u16* p, float a, float b, float c, float d){
  uint2 t; t.x = pack2(a,b); t.y = pack2(c,d);
  *(uint2*)p = t;
}

// ---------- misc: zero an int buffer ----------
__global__ __launch_bounds__(256) void zero_kernel(int* p, int n){
  int i = blockIdx.x*256 + threadIdx.x;
  if (i < n) p[i] = 0;
}

// ---------- stage W[128][128] fp32 -> LDS transposed bf16 Wt[n][k], stride 136 ----------
__device__ __forceinline__ void stageWt(const float* __restrict__ W, u16* Wt, int tid){
  const int n = tid & 127, khalf = tid >> 7;
#pragma unroll
  for (int g = 0; g < 16; ++g) {
    int k0 = khalf*64 + g*4;
    float w0 = W[(k0+0)*128 + n];
    float w1 = W[(k0+1)*128 + n];
    float w2 = W[(k0+2)*128 + n];
    float w3 = W[(k0+3)*128 + n];
    uint2 t; t.x = pack2(w0,w1); t.y = pack2(w2,w3);
    *(uint2*)&Wt[n*136 + k0] = t;
  }
}

// ---------- MFMA GEMM core: C[N,128](bf16) = A[N,128] @ W[128,128] ----------
// Layouts (16x16x32 bf16): A[m=lane&15][k=quad*8+j], B[k=quad*8+j][n=lane&15],
// D[row=quad*4+reg][col=lane&15].
__device__ __forceinline__ void gemm_core(
    const float* __restrict__ Af, const u16* __restrict__ Ah,
    const float* __restrict__ W, u16* __restrict__ C, int N, int brow,
    u16* Wt, int tid)
{
  stageWt(W, Wt, tid);
  __syncthreads();

  const int w = tid >> 6, lane = tid & 63;
  const int m = lane & 15, quad = lane >> 4;
  const int rowBase = brow*64 + w*16;
  int arow = rowBase + m;
  if (arow >= N) arow = N-1;

  bf16x8 af[4];
  if (Ah) {
#pragma unroll
    for (int kt=0; kt<4; ++kt)
      af[kt] = *(const bf16x8*)(Ah + (size_t)arow*128 + kt*32 + quad*8);
  } else {
#pragma unroll
    for (int kt=0; kt<4; ++kt) {
      float v[8]; load8f(Af + (size_t)arow*128 + kt*32 + quad*8, v);
      bf16x8 t;
#pragma unroll
      for (int j=0;j<8;++j) t[j] = (short)f2bf(v[j]);
      af[kt] = t;
    }
  }

#pragma unroll
  for (int jt=0; jt<8; ++jt) {
    f32x4 acc = {0.f,0.f,0.f,0.f};
#pragma unroll
    for (int kt=0; kt<4; ++kt) {
      bf16x8 bf = *(const bf16x8*)&Wt[(jt*16+m)*136 + kt*32 + quad*8];
      acc = __builtin_amdgcn_mfma_f32_16x16x32_bf16(af[kt], bf, acc, 0, 0, 0);
    }
    const int col = jt*16 + m;
#pragma unroll
    for (int r=0;r<4;++r) {
      int rg = rowBase + quad*4 + r;
      if (rg < N) C[(size_t)rg*128 + col] = f2bf(acc[r]);
    }
  }
}

// dual GEMM: blocks [0,g1) -> side1, rest -> side2
__global__ __launch_bounds__(256) void gemm128_dual(
    const float* Af1, const u16* Ah1, const float* W1, u16* C1, int N1, int g1,
    const float* Af2, const u16* Ah2, const float* W2, u16* C2, int N2)
{
  __shared__ alignas(16) u16 Wt[128*136];
  const int b = blockIdx.x;
  if (b < g1) gemm_core(Af1, Ah1, W1, C1, N1, b,      Wt, threadIdx.x);
  else        gemm_core(Af2, Ah2, W2, C2, N2, b - g1, Wt, threadIdx.x);
}

// ---------- fused update core (MFMA): out = T + lrelu(Hy@latW) + prev ; S (+)= out ----------
__device__ __forceinline__ void update_core(
    const u16* __restrict__ T, const u16* __restrict__ Hy,
    const float* __restrict__ latW,
    const float* __restrict__ PrevF, const u16* __restrict__ PrevH,
    u16* __restrict__ Pout, float* __restrict__ S, int N, int initS,
    char* shmem, int tid)
{
  u16* Wt = (u16*)shmem;
  float* Gs = (float*)shmem;
  stageWt(latW, Wt, tid);
  __syncthreads();

  const int w = tid >> 6, lane = tid & 63;
  const int m = lane & 15, quad = lane >> 4;
  const int rowBase = (int)blockIdx.x; // unused placeholder
  (void)rowBase;
  return; // never called directly
}

// dual update kernel (body inlined twice to keep shared-mem simple)
__global__ __launch_bounds__(256) void update_dual(
    const u16* T1, const u16* Hy1, const float* W1,
    const float* PF1, const u16* PH1, u16* Po1, float* S1, int N1, int g1,
    const u16* T2, const u16* Hy2, const float* W2,
    const float* PF2, const u16* PH2, u16* Po2, float* S2, int N2, int initS)
{
  __shared__ alignas(16) char shmem[34816];  // union: Wt u16[128*136] | Gs f32[64*132]
  u16* Wt = (u16*)shmem;
  float* Gs = (float*)shmem;
  const int tid = threadIdx.x;
  const int b = blockIdx.x;

  const u16* T; const u16* Hy; const float* latW;
  const float* PrevF; const u16* PrevH; u16* Pout; float* S; int N; int brow;
  if (b < g1) { T=T1; Hy=Hy1; latW=W1; PrevF=PF1; PrevH=PH1; Pout=Po1; S=S1; N=N1; brow=b; }
  else        { T=T2; Hy=Hy2; latW=W2; PrevF=PF2; PrevH=PH2; Pout=Po2; S=S2; N=N2; brow=b-g1; }

  stageWt(latW, Wt, tid);
  __syncthreads();

  const int w = tid >> 6, lane = tid & 63;
  const int m = lane & 15, quad = lane >> 4;
  const int rowBase = brow*64;
  int arow = rowBase + w*16 + m;
  if (arow >= N) arow = N-1;

  bf16x8 af[4];
#pragma unroll
  for (int kt=0; kt<4; ++kt)
    af[kt] = *(const bf16x8*)(Hy + (size_t)arow*128 + kt*32 + quad*8);

  f32x4 acc[8];
#pragma unroll
  for (int jt=0; jt<8; ++jt) {
    f32x4 a = {0.f,0.f,0.f,0.f};
#pragma unroll
    for (int kt=0; kt<4; ++kt) {
      bf16x8 bf = *(const bf16x8*)&Wt[(jt*16+m)*136 + kt*32 + quad*8];
      a = __builtin_amdgcn_mfma_f32_16x16x32_bf16(af[kt], bf, a, 0, 0, 0);
    }
    acc[jt] = a;
  }
  __syncthreads();   // all Wt reads done; reuse LDS as Gs
#pragma unroll
  for (int jt=0; jt<8; ++jt) {
#pragma unroll
    for (int r=0;r<4;++r) {
      float x = acc[jt][r];
      Gs[(w*16 + quad*4 + r)*132 + jt*16 + m] = x > 0.f ? x : LEAKY*x;
    }
  }
  __syncthreads();

  const int c4 = (tid & 31) * 4;
  const int r0 = tid >> 5;
#pragma unroll
  for (int ri=0; ri<8; ++ri) {
    int lr = r0 + ri*8;           // 0..63
    int n = rowBase + lr;
    if (n >= N) continue;
    size_t off = (size_t)n*128 + c4;
    float gv[4]; load4f(&Gs[lr*132 + c4], gv);
    float tv[4], pv[4], ov[4];
    load4h(T + off, tv);
    if (PrevH) load4h(PrevH + off, pv);
    else       load4f(PrevF + off, pv);
#pragma unroll
    for (int cc=0;cc<4;++cc) ov[cc] = gv[cc] + tv[cc] + pv[cc];
    if (Pout)
      store4bf(&Pout[off], ov[0],ov[1],ov[2],ov[3]);
    if (initS) {
      float4 s; s.x=pv[0]+ov[0]; s.y=pv[1]+ov[1]; s.z=pv[2]+ov[2]; s.w=pv[3]+ov[3];
      *(float4*)&S[off] = s;
    } else {
      float4 s = *(const float4*)&S[off];
      s.x += ov[0]; s.y += ov[1]; s.z += ov[2]; s.w += ov[3];
      *(float4*)&S[off] = s;
    }
  }
}

// ---------- hyper reduce: partial[b] = Hy_chunk^T @ Lat_chunk (chunk = 256 rows) ----------
__global__ __launch_bounds__(256) void reduce_kernel(
    const u16* __restrict__ HyU, const u16* __restrict__ HyI,
    const float* __restrict__ LatUf, const u16* __restrict__ LatUh,
    const float* __restrict__ LatIf, const u16* __restrict__ LatIh,
    u16* __restrict__ part, int Nu, int Ni, int nbU)
{
  __shared__ float Hs[32*128];
  __shared__ float Ls[32*128];
  const int b = blockIdx.x;
  const u16* Hy; const float* Lf; const u16* Lh; int N, cstart;
  if (b < nbU) { Hy=HyU; Lf=LatUf; Lh=LatUh; N=Nu; cstart = b*256; }
  else         { Hy=HyI; Lf=LatIf; Lh=LatIh; N=Ni; cstart = (b-nbU)*256; }
  const int cend = (N < cstart+256) ? N : (cstart+256);
  const int tid = threadIdx.x;
  const int ty = tid >> 4, tx = tid & 15;
  const int h0 = ty*8;
  const int dA = tx*4, dB = tx*4+64;
  float acc[8][8];
#pragma unroll
  for (int a=0;a<8;++a)
#pragma unroll
    for (int c=0;c<8;++c) acc[a][c]=0.f;

  for (int t0 = cstart; t0 < cend; t0 += 32) {
#pragma unroll
    for (int j=0;j<2;++j) {
      int e = (j*256+tid)*8;
      int r = e>>7, k = e&127;
      int n = t0 + r;
      float v[8], u[8];
      if (n < cend) {
        load8h(Hy + (size_t)n*128+k, v);
        if (Lh) load8h(Lh + (size_t)n*128+k, u);
        else    load8f(Lf + (size_t)n*128+k, u);
      } else {
        for (int q=0;q<8;++q){v[q]=0.f;u[q]=0.f;}
      }
#pragma unroll
      for (int q=0;q<8;++q){ Hs[r*128+k+q]=v[q]; Ls[r*128+k+q]=u[q]; }
    }
    __syncthreads();
    for (int k=0;k<32;++k) {
      float4 hA = *(const float4*)&Hs[k*128+h0];
      float4 hB = *(const float4*)&Hs[k*128+h0+4];
      float4 lA = *(const float4*)&Ls[k*128+dA];
      float4 lB = *(const float4*)&Ls[k*128+dB];
      float hv[8]; float lv[8];
      hv[0]=hA.x;hv[1]=hA.y;hv[2]=hA.z;hv[3]=hA.w;hv[4]=hB.x;hv[5]=hB.y;hv[6]=hB.z;hv[7]=hB.w;
      lv[0]=lA.x;lv[1]=lA.y;lv[2]=lA.z;lv[3]=lA.w;lv[4]=lB.x;lv[5]=lB.y;lv[6]=lB.z;lv[7]=lB.w;
#pragma unroll
      for (int a=0;a<8;++a)
#pragma unroll
        for (int c=0;c<8;++c)
          acc[a][c] = fmaf(hv[a], lv[c], acc[a][c]);
    }
    __syncthreads();
  }
  u16* pb = part + (size_t)b*16384;
#pragma unroll
  for (int a=0;a<8;++a) {
    int h = h0+a;
    store4bf(&pb[h*128+dA], acc[a][0],acc[a][1],acc[a][2],acc[a][3]);
    store4bf(&pb[h*128+dB], acc[a][4],acc[a][5],acc[a][6],acc[a][7]);
  }
}

__global__ __launch_bounds__(256) void reduce2_kernel(
    const u16* __restrict__ part, float* __restrict__ Ru, float* __restrict__ Ri,
    int nbU, int nbI)
{
  const int e = blockIdx.x*256 + threadIdx.x;   // 0..16383
  const int side = blockIdx.y;
  const u16* p = part + (side ? (size_t)nbU*16384 : 0) + e;
  const int nb = side ? nbI : nbU;
  float s = 0.f;
  for (int j=0;j<nb;++j) s += bf2f(p[(size_t)j*16384]);
  if (side) Ri[e] = s; else Ru[e] = s;
}

// ---------- FC chain ----------
__global__ __launch_bounds__(128) void fc_kernel(
    const float* __restrict__ Ru, const float* __restrict__ Ri,
    const float* __restrict__ W3u, const float* __restrict__ W3i,
    float* __restrict__ latU, float* __restrict__ latI)
{
  __shared__ float cur[128];
  const int h = threadIdx.x;
  const int d = blockIdx.x;
  const int side = blockIdx.y;
  const float* R  = side ? Ri  : Ru;
  const float* W3 = side ? W3i : W3u;
  float* lat      = side ? latI : latU;
  float x = R[h*128 + d];
  cur[h] = x > 0.f ? x : LEAKY*x;
  __syncthreads();
  for (int s=0;s<3;++s) {
    const float* w = W3 + s*16384 + h;
    float val = 0.f;
#pragma unroll 8
    for (int hp=0; hp<128; ++hp) val = fmaf(cur[hp], w[hp*128], val);
    val = (val > 0.f ? val : 0.f) + cur[h];
    __syncthreads();
    cur[h] = val;
    __syncthreads();
  }
  lat[h*128+d] = cur[h];
}

// ---------- CSR-based SpMM: T[row,:] = relu( sum_e val_e * Y[idx_e,:] ) ----------
__global__ __launch_bounds__(256) void spmm_kernel(
    const uint2* __restrict__ csr, const int* __restrict__ rowptr,
    const u16* __restrict__ Y, u16* __restrict__ T, int N, int Ncol, int E)
{
  const int lane = threadIdx.x & 63;
  const int row = blockIdx.x*4 + (threadIdx.x >> 6);
  if (row >= N) return;
  int e  = rowptr[row];
  int e1 = rowptr[row+1];
  if (e < 0) e = 0;
  if (e > E) e = E;
  if (e1 < e) e1 = e;
  if (e1 > E) e1 = E;
  const u32 cmax = (u32)(Ncol - 1);
  float a0=0.f, a1=0.f;
  const int c2 = lane*2;
  for (; e+4 <= e1; e += 4) {
    uint2 p0 = csr[e], p1 = csr[e+1], p2 = csr[e+2], p3 = csr[e+3];
    u32 i0 = p0.x < cmax ? p0.x : cmax;
    u32 i1 = p1.x < cmax ? p1.x : cmax;
    u32 i2 = p2.x < cmax ? p2.x : cmax;
    u32 i3 = p3.x < cmax ? p3.x : cmax;
    u32 y0 = *(const u32*)&Y[(size_t)i0*128 + c2];
    u32 y1 = *(const u32*)&Y[(size_t)i1*128 + c2];
    u32 y2 = *(const u32*)&Y[(size_t)i2*128 + c2];
    u32 y3 = *(const u32*)&Y[(size_t)i3*128 + c2];
    float v0 = __uint_as_float(p0.y), v1 = __uint_as_float(p1.y);
    float v2 = __uint_as_float(p2.y), v3 = __uint_as_float(p3.y);
    a0 = fmaf(v0, bflo(y0), a0); a1 = fmaf(v0, bfhi(y0), a1);
    a0 = fmaf(v1, bflo(y1), a0); a1 = fmaf(v1, bfhi(y1), a1);
    a0 = fmaf(v2, bflo(y2), a0); a1 = fmaf(v2, bfhi(y2), a1);
    a0 = fmaf(v3, bflo(y3), a0); a1 = fmaf(v3, bfhi(y3), a1);
  }
  for (; e < e1; ++e) {
    uint2 p0 = csr[e];
    u32 i0 = p0.x < cmax ? p0.x : cmax;
    u32 y0 = *(const u32*)&Y[(size_t)i0*128 + c2];
    float v0 = __uint_as_float(p0.y);
    a0 = fmaf(v0, bflo(y0), a0); a1 = fmaf(v0, bfhi(y0), a1);
  }
  store2bf(&T[(size_t)row*128 + c2], a0 > 0.f ? a0 : 0.f, a1 > 0.f ? a1 : 0.f);
}

// ---------- CSR build ----------
__global__ __launch_bounds__(256) void hist_kernel(
    const int* __restrict__ rows, const int* __restrict__ cols,
    int* cntU, int* cntI, int E, int Nu, int Ni)
{
  int e = blockIdx.x*256 + threadIdx.x;
  if (e < E) {
    int r = rows[e], c = cols[e];
    if ((unsigned)r < (unsigned)Nu) atomicAdd(&cntU[r],1);
    if ((unsigned)c < (unsigned)Ni) atomicAdd(&cntI[c],1);
  }
}

__global__ __launch_bounds__(256) void scan_local_kernel(
    const int* __restrict__ cntU, const int* __restrict__ cntI,
    int* rpU, int* rpI, int* bsU, int* bsI, int Nu, int Ni)
{
  const int side = blockIdx.y;
  const int Nn = side ? Ni : Nu;
  const int* cnt = side ? cntI : cntU;
  int* rp = side ? rpI : rpU;
  int* bs = side ? bsI : bsU;
  const int nb = (Nn + 4095) >> 12;
  if ((int)blockIdx.x >= nb) return;
  __shared__ int sa[256], sb[256];
  const int tid = threadIdx.x;
  const int base = blockIdx.x*4096 + tid*16;
  int v[16]; int sum = 0;
#pragma unroll
  for (int q=0;q<16;++q){ int idx = base+q; int x = (idx<Nn)?cnt[idx]:0; v[q]=x; sum+=x; }
  sa[tid] = sum; __syncthreads();
  int* src = sa; int* dst = sb;
  for (int off=1; off<256; off<<=1) {
    int x = src[tid] + ((tid>=off) ? src[tid-off] : 0);
    dst[tid] = x;
    __syncthreads();
    int* t = src; src = dst; dst = t;
  }
  const int incl = src[tid];
  int run = incl - sum;  // exclusive
#pragma unroll
  for (int q=0;q<16;++q){ int idx=base+q; if (idx<Nn) rp[idx]=run; run+=v[q]; }
  if (tid==255) bs[blockIdx.x] = incl;
}

__global__ void scan_blocks_kernel(int* bsU, int* bsI, int* rpU, int* rpI, int Nu, int Ni)
{
  if (threadIdx.x != 0) return;
  const int side = blockIdx.y;
  int* bs = side?bsI:bsU; int* rp = side?rpI:rpU;
  const int Nn = side?Ni:Nu;
  const int nb = (Nn+4095)>>12;
  int run = 0;
  for (int b=0;b<nb;++b){ int t=bs[b]; bs[b]=run; run+=t; }
  rp[Nn] = run;
}

__global__ __launch_bounds__(256) void scan_add_kernel(
    const int* bsU, const int* bsI, int* rpU, int* rpI, int Nu, int Ni)
{
  const int side = blockIdx.y;
  const int Nn = side?Ni:Nu;
  const int* bs = side?bsI:bsU;
  int* rp = side?rpI:rpU;
  const int nb = (Nn+4095)>>12;
  if ((int)blockIdx.x >= nb) return;
  const int add = bs[blockIdx.x];
  const int base = blockIdx.x*4096 + threadIdx.x*16;
#pragma unroll
  for (int q=0;q<16;++q){ int idx=base+q; if (idx<Nn) rp[idx]+=add; }
}

// windowed scatter: only place edges whose destination row is inside
// [u0,u1) (U-side) / [i0w,i1w) (I-side). Sequential window launches keep the
// active CSR region L2-resident so lines get fully packed before eviction.
__global__ __launch_bounds__(256) void scatter_kernel(
    const int* __restrict__ rows, const int* __restrict__ cols, const float* __restrict__ vals,
    const int* __restrict__ rpU, const int* __restrict__ rpI,
    int* curU, int* curI, uint2* csrU, uint2* csrI, int E, int Nu, int Ni,
    int u0, int u1, int i0w, int i1w)
{
  int e = blockIdx.x*256 + threadIdx.x;
  if (e >= E) return;
  int r = rows[e], c = cols[e];
  if ((unsigned)r < (unsigned)Nu && (unsigned)c < (unsigned)Ni) {
    u32 vb = __float_as_uint(vals[e]);
    if (r >= u0 && r < u1) {
      int su = rpU[r] + atomicAdd(&curU[r], 1);
      if ((unsigned)su < (unsigned)E) { uint2 t; t.x=(u32)c; t.y=vb; csrU[su]=t; }
    }
    if (c >= i0w && c < i1w) {
      int si = rpI[c] + atomicAdd(&curI[c], 1);
      if ((unsigned)si < (unsigned)E) { uint2 t; t.x=(u32)r; t.y=vb; csrI[si]=t; }
    }
  }
}

// ---------- host ----------
extern "C" void kernel_launch(void* const* d_in, const int* in_sizes, int n_in,
                              void* d_out, int out_size, void* d_ws, size_t ws_size,
                              hipStream_t stream)
{
  const float* uE     = (const float*)d_in[0];
  const float* iE     = (const float*)d_in[1];
  const float* uhyper = (const float*)d_in[2];
  const float* ihyper = (const float*)d_in[3];
  const float* vals   = (const float*)d_in[4];
  const float* WhU    = (const float*)d_in[5];  // [L,3,128,128]
  const float* WhI    = (const float*)d_in[6];
  const float* WgU    = (const float*)d_in[7];  // [L,128,128]
  const float* WgI    = (const float*)d_in[8];
  const int*   rows   = (const int*)d_in[9];
  const int*   cols   = (const int*)d_in[10];
  const int U = in_sizes[0]/128;
  const int I = in_sizes[1]/128;
  const int E = in_sizes[4];
  const int L = in_sizes[7]/(128*128);
  (void)n_in; (void)out_size;

  float* Su = (float*)d_out;
  float* Si = Su + (size_t)U*128;

  char* base0 = (char*)d_ws;
  u16* uuH; u16* iiH; u16* PU; u16* PI; u16* YU; u16* TU; u16* pool3;
  uint2* csrU; uint2* csrI; int* rpU; int* rpI; int* cntU; int* cntI;
  int* bsU; int* bsI; float* Ru; float* Ri; float* latU; float* latI;
  {
    size_t off = 0;
    #define ALLOC(var, type, bytes) var = (type)(base0 + off); off = (off + (bytes) + 255) & ~(size_t)255;
    ALLOC(uuH,  u16*, (size_t)U*128*2)
    ALLOC(iiH,  u16*, (size_t)I*128*2)
    ALLOC(PU,   u16*, (size_t)U*128*2)
    ALLOC(PI,   u16*, (size_t)I*128*2)
    ALLOC(YU,   u16*, (size_t)U*128*2)      // Y_U; later reused as reduce partials
    ALLOC(TU,   u16*, (size_t)U*128*2)
    ALLOC(pool3,u16*, (size_t)I*128*2)      // Y_I then T_I
    ALLOC(csrU, uint2*, (size_t)E*8)
    ALLOC(csrI, uint2*, (size_t)E*8)
    ALLOC(rpU,  int*, (size_t)(U+1)*4)
    ALLOC(rpI,  int*, (size_t)(I+1)*4)
    ALLOC(cntU, int*, (size_t)U*4)
    ALLOC(cntI, int*, (size_t)I*4)
    ALLOC(bsU,  int*, 64*4)
    ALLOC(bsI,  int*, 64*4)
    ALLOC(Ru,   float*, 16384*4)
    ALLOC(Ri,   float*, 16384*4)
    ALLOC(latU, float*, 16384*4)
    ALLOC(latI, float*, 16384*4)
    #undef ALLOC
    if (off > ws_size) return;   // clean bail, graph-safe
  }
  const int cntN = (int)(((size_t)((char*)bsU - (char*)cntU)) / 4);

  const int nbU = (U+4095)>>12, nbI = (I+4095)>>12;
  const int nbMax = nbU > nbI ? nbU : nbI;
  const int rbU = (U+255)>>8, rbI = (I+255)>>8;   // reduce chunks (256 rows)
  const int gU = (U+63)/64, gI = (I+63)/64;        // MFMA gemm/update grids

  // --- CSR build (both directions) ---
  zero_kernel<<<(cntN+255)/256, 256, 0, stream>>>(cntU, cntN);
  hist_kernel<<<(E+255)/256, 256, 0, stream>>>(rows, cols, cntU, cntI, E, U, I);
  scan_local_kernel<<<dim3(nbMax,2), 256, 0, stream>>>(cntU,cntI,rpU,rpI,bsU,bsI,U,I);
  scan_blocks_kernel<<<dim3(1,2), 64, 0, stream>>>(bsU,bsI,rpU,rpI,U,I);
  scan_add_kernel<<<dim3(nbMax,2), 256, 0, stream>>>(bsU,bsI,rpU,rpI,U,I);
  zero_kernel<<<(cntN+255)/256, 256, 0, stream>>>(cntU, cntN);
  // 4 sequential windowed passes; each pass's active CSR region ~6.4 MB
  for (int wnd = 0; wnd < 4; ++wnd) {
    int u0 = (int)(((long long)wnd   * U) / 4);
    int u1 = (int)(((long long)(wnd+1) * U) / 4);
    int i0w = (int)(((long long)wnd   * I) / 4);
    int i1w = (int)(((long long)(wnd+1) * I) / 4);
    scatter_kernel<<<(E+255)/256, 256, 0, stream>>>(
        rows, cols, vals, rpU, rpI, cntU, cntI, csrU, csrI, E, U, I,
        u0, u1, i0w, i1w);
  }

  // --- hyper embeddings (merged U+I) ---
  gemm128_dual<<<gU+gI, 256, 0, stream>>>(uE, (const u16*)0, uhyper, uuH, U, gU,
                                          iE, (const u16*)0, ihyper, iiH, I);

  for (int l=0; l<L; ++l) {
    const float* wgu = WgU + (size_t)l*16384;
    const float* wgi = WgI + (size_t)l*16384;
    const float* whu = WhU + (size_t)l*3*16384;
    const float* whi = WhI + (size_t)l*3*16384;
    const bool last = (l == L-1);
    if (l == 0) {
      // Y_I = iE@WgU -> pool3 ; Y_U = uE@WgI -> YU  (merged)
      gemm128_dual<<<gI+gU, 256, 0, stream>>>(iE, (const u16*)0, wgu, pool3, I, gI,
                                              uE, (const u16*)0, wgi, YU, U);
      spmm_kernel<<<(U+3)/4, 256, 0, stream>>>(csrU, rpU, pool3, TU, U, I, E);   // T_U
      spmm_kernel<<<(I+3)/4, 256, 0, stream>>>(csrI, rpI, YU, pool3, I, U, E);   // T_I (pool3 reused)
      reduce_kernel<<<rbU+rbI, 256, 0, stream>>>(uuH,iiH, uE,(const u16*)0, iE,(const u16*)0, YU,U,I,rbU);
      reduce2_kernel<<<dim3(64,2), 256, 0, stream>>>(YU, Ru, Ri, rbU, rbI);
      fc_kernel<<<dim3(128,2), 128, 0, stream>>>(Ru,Ri,whu,whi,latU,latI);
      update_dual<<<gU+gI, 256, 0, stream>>>(
          TU,    uuH, latU, uE, (const u16*)0, PU, Su, U, gU,
          pool3, iiH, latI, iE, (const u16*)0, PI, Si, I, 1);
    } else {
      gemm128_dual<<<gI+gU, 256, 0, stream>>>((const float*)0, PI, wgu, pool3, I, gI,
                                              (const float*)0, PU, wgi, YU, U);
      spmm_kernel<<<(U+3)/4, 256, 0, stream>>>(csrU, rpU, pool3, TU, U, I, E);
      spmm_kernel<<<(I+3)/4, 256, 0, stream>>>(csrI, rpI, YU, pool3, I, U, E);
      reduce_kernel<<<rbU+rbI, 256, 0, stream>>>(uuH,iiH, (const float*)0,PU, (const float*)0,PI, YU,U,I,rbU);
      reduce2_kernel<<<dim3(64,2), 256, 0, stream>>>(YU, Ru, Ri, rbU, rbI);
      fc_kernel<<<dim3(128,2), 128, 0, stream>>>(Ru,Ri,whu,whi,latU,latI);
      update_dual<<<gU+gI, 256, 0, stream>>>(
          TU,    uuH, latU, (const float*)0, PU, last?(u16*)0:PU, Su, U, gU,
          pool3, iiH, latI, (const float*)0, PI, last?(u16*)0:PI, Si, I, 0);
    }
  }
}